// Round 5
// baseline (503.102 us; speedup 1.0000x reference)
//
#include <hip/hip_runtime.h>
#include <hip/hip_bf16.h>
#include <hip/hip_fp16.h>
#include <cstdint>

#define HIDC 128
#define FIXSCALE 4194304.0f        // 2^22
#define FIXINV   (1.0f / 4194304.0f)

// ---------------- zero degcnt (u64 per node) ------------------------------
__global__ void init_kernel(unsigned long long* __restrict__ degcnt, int n_nodes) {
    int i = blockIdx.x * blockDim.x + threadIdx.x;
    if (i < n_nodes) degcnt[i] = 0ull;
}

// ------ fused: hist (first histBlocks) + gemm1 x@W1->fp16 (rest) ----------
// hist: grid-strided, 4 independent returning atomics in flight per thread.
// gemm1: no LDS (x row is wave-uniform scalar-cached, W1 rows coalesced+L1).
__global__ __launch_bounds__(256) void hist_gemm1_kernel(
        const int* __restrict__ ei, const float* __restrict__ ea,
        unsigned long long* __restrict__ degcnt, int* __restrict__ rank, int E,
        const float* __restrict__ x, const float* __restrict__ W1,
        __half* __restrict__ h1, int n_nodes, int histBlocks) {
    int b = blockIdx.x;
    if (b < histBlocks) {
        int tot = histBlocks * 256;
        int tid = b * 256 + threadIdx.x;
#pragma unroll
        for (int j = 0; j < 4; ++j) {
            int e = tid + j * tot;
            if (e < E) {
                int d = ei[E + e];
                unsigned int fx = (unsigned int)(ea[e] * FIXSCALE + 0.5f);
                unsigned long long old =
                    atomicAdd(&degcnt[d], (1ull << 32) | (unsigned long long)fx);
                rank[e] = (int)(old >> 32);
            }
        }
    } else {
        int gb = b - histBlocks;
        int nodeBase = gb * 16;
        int t = threadIdx.x;
        int d = t & 127;
        int half = t >> 7;                 // 0/1
        for (int ni = half; ni < 16; ni += 2) {
            int node = nodeBase + ni;
            if (node >= n_nodes) break;
            float acc = 0.f;
#pragma unroll
            for (int k = 0; k < 64; ++k)
                acc += x[(size_t)node * 64 + k] * W1[k * 128 + d];
            h1[(size_t)node * 128 + d] = __float2half(acc);
        }
    }
}

// ---------------- scan phase A: dinv + per-block count sums ---------------
__global__ __launch_bounds__(256) void dinv_blocksum_kernel(const unsigned long long* __restrict__ degcnt,
                                                            float* __restrict__ dinv,
                                                            int* __restrict__ blocksum, int n_nodes) {
    __shared__ int sh[256];
    int t = threadIdx.x;
    int i = blockIdx.x * 256 + t;
    int cnt = 0;
    if (i < n_nodes) {
        unsigned long long v = degcnt[i];
        cnt = (int)(v >> 32);
        float deg = 1.0f + (float)(unsigned int)(v & 0xffffffffull) * FIXINV;
        dinv[i] = rsqrtf(deg);
    }
    sh[t] = cnt;
    __syncthreads();
    for (int off = 128; off > 0; off >>= 1) {
        if (t < off) sh[t] += sh[t + off];
        __syncthreads();
    }
    if (t == 0) blocksum[blockIdx.x] = sh[0];
}

// ---------------- scan phase B: exclusive scan of block sums (1 block) ----
__global__ __launch_bounds__(256) void scan_blocksums_kernel(const int* __restrict__ blocksum,
                                                             int* __restrict__ blockoff, int nb) {
    __shared__ int sh[256];
    int t = threadIdx.x;
    int v = (t < nb) ? blocksum[t] : 0;
    sh[t] = v;
    __syncthreads();
    for (int off = 1; off < 256; off <<= 1) {
        int u = (t >= off) ? sh[t - off] : 0;
        __syncthreads();
        sh[t] += u;
        __syncthreads();
    }
    if (t < nb) blockoff[t] = sh[t] - v;       // exclusive
}

// ---------------- scan phase C: rowptr ------------------------------------
__global__ __launch_bounds__(256) void rowptr_kernel(const unsigned long long* __restrict__ degcnt,
                                                     const int* __restrict__ blockoff,
                                                     int* __restrict__ rowptr, int n_nodes) {
    __shared__ int sh[256];
    int t = threadIdx.x;
    int i = blockIdx.x * 256 + t;
    int cnt = (i < n_nodes) ? (int)(degcnt[i] >> 32) : 0;
    sh[t] = cnt;
    __syncthreads();
    for (int off = 1; off < 256; off <<= 1) {
        int u = (t >= off) ? sh[t - off] : 0;
        __syncthreads();
        sh[t] += u;
        __syncthreads();
    }
    if (i < n_nodes) {
        int excl = blockoff[blockIdx.x] + sh[t] - cnt;
        rowptr[i] = excl;
        if (i == n_nodes - 1) rowptr[n_nodes] = excl + cnt;
    }
}

// ------ fill CSR: atomic-free scatter via rowptr[d] + rank[e] -------------
__global__ void fill_kernel(const int* __restrict__ ei, const float* __restrict__ ea,
                            const float* __restrict__ dinv, const int* __restrict__ rowptr,
                            const int* __restrict__ rank,
                            int2* __restrict__ csr, int E) {
    int e = blockIdx.x * blockDim.x + threadIdx.x;
    if (e >= E) return;
    int s = ei[e];
    int d = ei[E + e];
    float c = dinv[s] * ea[e] * dinv[d];
    int pos = rowptr[d] + rank[e];
    csr[pos] = make_int2(s, __float_as_int(c));
}

// ------ tiled GEMM: out[n,128] = A[n,128] @ W[128,128], fp16 output -------
template <int K>
__global__ __launch_bounds__(256) void gemm_tiled(const float* __restrict__ A,
                                                  const float* __restrict__ W,
                                                  __half* __restrict__ out, int n_nodes) {
    __shared__ float sW[K * 128];
    __shared__ float sX[16 * K];
    int t = threadIdx.x;
    int nodeBase = blockIdx.x * 16;
    for (int i = t; i < K * 128; i += 256) sW[i] = W[i];
    int nAvail = n_nodes - nodeBase; if (nAvail > 16) nAvail = 16;
    for (int i = t; i < nAvail * K; i += 256) sX[i] = A[(size_t)nodeBase * K + i];
    __syncthreads();
    int d = t & 127;
    for (int ni = (t >> 7); ni < nAvail; ni += 2) {
        float acc = 0.f;
#pragma unroll
        for (int k = 0; k < K; ++k) acc += sX[ni * K + k] * sW[k * 128 + d];
        out[(size_t)(nodeBase + ni) * 128 + d] = __float2half(acc);
    }
}

// ------ CSR gather-aggregate (fp16 h) + self loop + bias + ReLU -----------
__global__ __launch_bounds__(256) void agg_kernel(const __half* __restrict__ h,
                                                  const int* __restrict__ rowptr,
                                                  const int2* __restrict__ csr,
                                                  const float* __restrict__ dinv,
                                                  const float* __restrict__ bias,
                                                  float* __restrict__ out, int n_nodes) {
    int wave = threadIdx.x >> 6;
    int lane = threadIdx.x & 63;
    int node = blockIdx.x * 4 + wave;
    if (node >= n_nodes) return;
    int beg = rowptr[node];
    int end = rowptr[node + 1];
    float a0 = 0.f, a1 = 0.f;
    int e = beg;
    for (; e + 16 <= end; e += 16) {
        int2 p[16];
#pragma unroll
        for (int j = 0; j < 16; ++j) p[j] = csr[e + j];
        __half2 v[16];
#pragma unroll
        for (int j = 0; j < 16; ++j)
            v[j] = *(reinterpret_cast<const __half2*>(h + (size_t)p[j].x * HIDC) + lane);
#pragma unroll
        for (int j = 0; j < 16; ++j) {
            float c = __int_as_float(p[j].y);
            float2 f = __half22float2(v[j]);
            a0 += c * f.x; a1 += c * f.y;
        }
    }
    for (; e + 4 <= end; e += 4) {
        int2 p[4];
#pragma unroll
        for (int j = 0; j < 4; ++j) p[j] = csr[e + j];
        __half2 v[4];
#pragma unroll
        for (int j = 0; j < 4; ++j)
            v[j] = *(reinterpret_cast<const __half2*>(h + (size_t)p[j].x * HIDC) + lane);
#pragma unroll
        for (int j = 0; j < 4; ++j) {
            float c = __int_as_float(p[j].y);
            float2 f = __half22float2(v[j]);
            a0 += c * f.x; a1 += c * f.y;
        }
    }
    for (; e < end; ++e) {
        int2 p = csr[e];
        float c = __int_as_float(p.y);
        float2 f = __half22float2(*(reinterpret_cast<const __half2*>(h + (size_t)p.x * HIDC) + lane));
        a0 += c * f.x; a1 += c * f.y;
    }
    float di = dinv[node];
    float selfc = di * di;
    float2 fn = __half22float2(*(reinterpret_cast<const __half2*>(h + (size_t)node * HIDC) + lane));
    a0 += selfc * fn.x;
    a1 += selfc * fn.y;
    float2 bb = *(reinterpret_cast<const float2*>(bias) + lane);
    a0 = fmaxf(a0 + bb.x, 0.f);
    a1 = fmaxf(a1 + bb.y, 0.f);
    float2* op = reinterpret_cast<float2*>(out + (size_t)node * HIDC) + lane;
    *op = make_float2(a0, a1);
}

// ------ fused pool + MLP head: block per graph ----------------------------
__global__ __launch_bounds__(128) void pool_mlp_kernel(const float* __restrict__ h,
                                                       const int* __restrict__ batch,
                                                       const float* __restrict__ Wm1,
                                                       const float* __restrict__ bm1,
                                                       const float* __restrict__ Wm2,
                                                       const float* __restrict__ bm2,
                                                       float* __restrict__ out,
                                                       int n_nodes, int out_dim) {
    int g = blockIdx.x;
    int t = threadIdx.x;
    __shared__ int sb[2];
    if (t < 2) {
        int target = g + t;
        int lo = 0, hi = n_nodes;
        while (lo < hi) { int mid = (lo + hi) >> 1; if (batch[mid] < target) lo = mid + 1; else hi = mid; }
        sb[t] = lo;
    }
    __syncthreads();
    int beg = sb[0], end = sb[1];
    float p = 0.f;
    for (int i = beg; i < end; ++i) p += h[(size_t)i * 128 + t];
    __shared__ float row[128];
    __shared__ float z[128];
    row[t] = p;
    __syncthreads();
    float acc = bm1[t];
#pragma unroll 8
    for (int k = 0; k < 128; ++k) acc += row[k] * Wm1[k * 128 + t];
    z[t] = fmaxf(acc, 0.f);
    __syncthreads();
    if (t < out_dim) {
        float o = bm2[t];
#pragma unroll 8
        for (int k = 0; k < 128; ++k) o += z[k] * Wm2[k * out_dim + t];
        out[g * out_dim + t] = o;
    }
}

extern "C" void kernel_launch(void* const* d_in, const int* in_sizes, int n_in,
                              void* d_out, int out_size, void* d_ws, size_t ws_size,
                              hipStream_t stream) {
    const float* x   = (const float*)d_in[0];
    const int*   ei  = (const int*)d_in[1];
    const int*   bat = (const int*)d_in[2];
    const float* ea  = (const float*)d_in[3];
    const float* W1  = (const float*)d_in[4];
    const float* b1  = (const float*)d_in[5];
    const float* W2  = (const float*)d_in[6];
    const float* b2  = (const float*)d_in[7];
    const float* Wm1 = (const float*)d_in[8];
    const float* bm1 = (const float*)d_in[9];
    const float* Wm2 = (const float*)d_in[10];
    const float* bm2 = (const float*)d_in[11];
    float* out = (float*)d_out;

    const int N = in_sizes[2];           // 50000 nodes
    const int E = in_sizes[1] / 2;       // 1.6M edges
    const int N_GRAPHS = 512;
    const int OUT_DIM = out_size / N_GRAPHS;  // 10

    // workspace layout (all 256B-aligned)
    char* ws = (char*)d_ws;
    size_t off = 0;
    auto alloc = [&](size_t bytes) { char* p = ws + off; off += (bytes + 255) & ~size_t(255); return p; };
    __half* bufH    = (__half*)alloc((size_t)N * HIDC * 2);  // h1 then h2 (gathered, fp16)
    float*  bufB    = (float*)alloc((size_t)N * HIDC * 4);   // hr1 then hr2 (fp32)
    int2*   csr     = (int2*) alloc((size_t)E * 8);
    int*    rank    = (int*)  alloc((size_t)E * 4);
    unsigned long long* degcnt = (unsigned long long*)alloc((size_t)N * 8);
    float*  dinv    = (float*)alloc((size_t)N * 4);
    int*    rowptr  = (int*)  alloc((size_t)(N + 1) * 4);
    int*    blocksum= (int*)  alloc(1024);
    int*    blockoff= (int*)  alloc(1024);

    const int B = 256;
    int gN = (N + B - 1) / B;            // 196 blocks
    int gE = (E + B - 1) / B;

    int histBlocks = (E + B * 4 - 1) / (B * 4);      // 1563
    int gemmBlocks = (N + 15) / 16;                  // 3125

    // 1. zero degcnt
    init_kernel<<<gN, B, 0, stream>>>(degcnt, N);
    // 2. fused hist (atomics, rank) + gemm1 (x@W1 -> fp16 h1)
    hist_gemm1_kernel<<<histBlocks + gemmBlocks, B, 0, stream>>>(
        ei, ea, degcnt, rank, E, x, W1, bufH, N, histBlocks);
    // 3a. dinv + block sums
    dinv_blocksum_kernel<<<gN, B, 0, stream>>>(degcnt, dinv, blocksum, N);
    // 3b. scan block sums
    scan_blocksums_kernel<<<1, 256, 0, stream>>>(blocksum, blockoff, gN);
    // 3c. rowptr
    rowptr_kernel<<<gN, B, 0, stream>>>(degcnt, blockoff, rowptr, N);
    // 4. CSR fill (atomic-free scatter)
    fill_kernel<<<gE, B, 0, stream>>>(ei, ea, dinv, rowptr, rank, csr, E);
    // 5. hr1 = relu(aggregate(h1) + b1)  (fp32)
    agg_kernel<<<(N + 3) / 4, 256, 0, stream>>>(bufH, rowptr, csr, dinv, b1, bufB, N);
    // 6. h2 = hr1 @ W2  (fp16 out)
    gemm_tiled<128><<<(N + 15) / 16, 256, 0, stream>>>(bufB, W2, bufH, N);
    // 7. hr2 = relu(aggregate(h2) + b2)  (fp32)
    agg_kernel<<<(N + 3) / 4, 256, 0, stream>>>(bufH, rowptr, csr, dinv, b2, bufB, N);
    // 8. fused pool + MLP head
    pool_mlp_kernel<<<N_GRAPHS, 128, 0, stream>>>(bufB, bat, Wm1, bm1, Wm2, bm2, out, N, OUT_DIM);
}

// Round 6
// 437.436 us; speedup vs baseline: 1.1501x; 1.1501x over previous
//
#include <hip/hip_runtime.h>
#include <hip/hip_bf16.h>
#include <hip/hip_fp16.h>
#include <cstdint>

#define HIDC 128
#define FIXSCALE 4194304.0f        // 2^22
#define FIXINV   (1.0f / 4194304.0f)
#define NSHARD 4

// ---------------- zero degcnt planes (u64 per node per shard) -------------
__global__ void init_kernel(unsigned long long* __restrict__ degcnt, int n4) {
    int i = blockIdx.x * blockDim.x + threadIdx.x;
    if (i < n4) degcnt[i] = 0ull;
}

// ------ hist: sharded planes; one u64 atomic per edge; rank = old count ---
__global__ void hist_kernel(const int* __restrict__ ei, const float* __restrict__ ea,
                            unsigned long long* __restrict__ degcnt,
                            int* __restrict__ rank, int E, int N) {
    int e = blockIdx.x * blockDim.x + threadIdx.x;
    if (e >= E) return;
    int d = ei[E + e];                         // dst
    int s = e & (NSHARD - 1);
    unsigned int fx = (unsigned int)(ea[e] * FIXSCALE + 0.5f);
    unsigned long long old =
        atomicAdd(&degcnt[(size_t)s * N + d], (1ull << 32) | (unsigned long long)fx);
    rank[e] = (int)(old >> 32);
}

// ------ scan phase A: dinv + cnt + shard offsets + per-block count sums ---
__global__ __launch_bounds__(256) void dinv_blocksum_kernel(
        const unsigned long long* __restrict__ degcnt,
        float* __restrict__ dinv, int* __restrict__ cnt_out,
        int* __restrict__ soff, int* __restrict__ blocksum, int n_nodes) {
    __shared__ int sh[256];
    int t = threadIdx.x;
    int i = blockIdx.x * 256 + t;
    int cnt = 0;
    if (i < n_nodes) {
        unsigned long long v0 = degcnt[i];
        unsigned long long v1 = degcnt[(size_t)n_nodes + i];
        unsigned long long v2 = degcnt[(size_t)2 * n_nodes + i];
        unsigned long long v3 = degcnt[(size_t)3 * n_nodes + i];
        int c0 = (int)(v0 >> 32), c1 = (int)(v1 >> 32);
        int c2 = (int)(v2 >> 32), c3 = (int)(v3 >> 32);
        cnt = c0 + c1 + c2 + c3;
        unsigned long long fxsum = (v0 & 0xffffffffull) + (v1 & 0xffffffffull)
                                 + (v2 & 0xffffffffull) + (v3 & 0xffffffffull);
        float deg = 1.0f + (float)fxsum * FIXINV;
        dinv[i] = rsqrtf(deg);
        cnt_out[i] = cnt;
        soff[i] = 0;
        soff[(size_t)n_nodes + i] = c0;
        soff[(size_t)2 * n_nodes + i] = c0 + c1;
        soff[(size_t)3 * n_nodes + i] = c0 + c1 + c2;
    }
    sh[t] = cnt;
    __syncthreads();
    for (int off = 128; off > 0; off >>= 1) {
        if (t < off) sh[t] += sh[t + off];
        __syncthreads();
    }
    if (t == 0) blocksum[blockIdx.x] = sh[0];
}

// ---------------- scan phase B: exclusive scan of block sums (1 block) ----
__global__ __launch_bounds__(256) void scan_blocksums_kernel(const int* __restrict__ blocksum,
                                                             int* __restrict__ blockoff, int nb) {
    __shared__ int sh[256];
    int t = threadIdx.x;
    int v = (t < nb) ? blocksum[t] : 0;
    sh[t] = v;
    __syncthreads();
    for (int off = 1; off < 256; off <<= 1) {
        int u = (t >= off) ? sh[t - off] : 0;
        __syncthreads();
        sh[t] += u;
        __syncthreads();
    }
    if (t < nb) blockoff[t] = sh[t] - v;       // exclusive
}

// ---------------- scan phase C: rowptr ------------------------------------
__global__ __launch_bounds__(256) void rowptr_kernel(const int* __restrict__ cnt_in,
                                                     const int* __restrict__ blockoff,
                                                     int* __restrict__ rowptr, int n_nodes) {
    __shared__ int sh[256];
    int t = threadIdx.x;
    int i = blockIdx.x * 256 + t;
    int cnt = (i < n_nodes) ? cnt_in[i] : 0;
    sh[t] = cnt;
    __syncthreads();
    for (int off = 1; off < 256; off <<= 1) {
        int u = (t >= off) ? sh[t - off] : 0;
        __syncthreads();
        sh[t] += u;
        __syncthreads();
    }
    if (i < n_nodes) {
        int excl = blockoff[blockIdx.x] + sh[t] - cnt;
        rowptr[i] = excl;
        if (i == n_nodes - 1) rowptr[n_nodes] = excl + cnt;
    }
}

// ------ fill CSR: atomic-free scatter: rowptr[d] + soff[s][d] + rank[e] ---
__global__ void fill_kernel(const int* __restrict__ ei, const float* __restrict__ ea,
                            const float* __restrict__ dinv, const int* __restrict__ rowptr,
                            const int* __restrict__ soff, const int* __restrict__ rank,
                            int2* __restrict__ csr, int E, int N) {
    int e = blockIdx.x * blockDim.x + threadIdx.x;
    if (e >= E) return;
    int s = ei[e];
    int d = ei[E + e];
    int sh = e & (NSHARD - 1);
    float c = dinv[s] * ea[e] * dinv[d];
    int pos = rowptr[d] + soff[(size_t)sh * N + d] + rank[e];
    csr[pos] = make_int2(s, __float_as_int(c));
}

// ------ tiled GEMM: out[n,128] = A[n,K] @ W[K,128], fp16 output -----------
template <int K>
__global__ __launch_bounds__(256) void gemm_tiled(const float* __restrict__ A,
                                                  const float* __restrict__ W,
                                                  __half* __restrict__ out, int n_nodes) {
    __shared__ float sW[K * 128];
    __shared__ float sX[16 * K];
    int t = threadIdx.x;
    int nodeBase = blockIdx.x * 16;
    for (int i = t; i < K * 128; i += 256) sW[i] = W[i];
    int nAvail = n_nodes - nodeBase; if (nAvail > 16) nAvail = 16;
    for (int i = t; i < nAvail * K; i += 256) sX[i] = A[(size_t)nodeBase * K + i];
    __syncthreads();
    int d = t & 127;
    for (int ni = (t >> 7); ni < nAvail; ni += 2) {
        float acc = 0.f;
#pragma unroll
        for (int k = 0; k < K; ++k) acc += sX[ni * K + k] * sW[k * 128 + d];
        out[(size_t)(nodeBase + ni) * 128 + d] = __float2half(acc);
    }
}

// ------ CSR gather-aggregate (fp16 h) + self loop + bias + ReLU -----------
__global__ __launch_bounds__(256) void agg_kernel(const __half* __restrict__ h,
                                                  const int* __restrict__ rowptr,
                                                  const int2* __restrict__ csr,
                                                  const float* __restrict__ dinv,
                                                  const float* __restrict__ bias,
                                                  float* __restrict__ out, int n_nodes) {
    int wave = threadIdx.x >> 6;
    int lane = threadIdx.x & 63;
    int node = blockIdx.x * 4 + wave;
    if (node >= n_nodes) return;
    int beg = rowptr[node];
    int end = rowptr[node + 1];
    float a0 = 0.f, a1 = 0.f;
    int e = beg;
    for (; e + 16 <= end; e += 16) {
        int2 p[16];
#pragma unroll
        for (int j = 0; j < 16; ++j) p[j] = csr[e + j];
        __half2 v[16];
#pragma unroll
        for (int j = 0; j < 16; ++j)
            v[j] = *(reinterpret_cast<const __half2*>(h + (size_t)p[j].x * HIDC) + lane);
#pragma unroll
        for (int j = 0; j < 16; ++j) {
            float c = __int_as_float(p[j].y);
            float2 f = __half22float2(v[j]);
            a0 += c * f.x; a1 += c * f.y;
        }
    }
    for (; e + 4 <= end; e += 4) {
        int2 p[4];
#pragma unroll
        for (int j = 0; j < 4; ++j) p[j] = csr[e + j];
        __half2 v[4];
#pragma unroll
        for (int j = 0; j < 4; ++j)
            v[j] = *(reinterpret_cast<const __half2*>(h + (size_t)p[j].x * HIDC) + lane);
#pragma unroll
        for (int j = 0; j < 4; ++j) {
            float c = __int_as_float(p[j].y);
            float2 f = __half22float2(v[j]);
            a0 += c * f.x; a1 += c * f.y;
        }
    }
    for (; e < end; ++e) {
        int2 p = csr[e];
        float c = __int_as_float(p.y);
        float2 f = __half22float2(*(reinterpret_cast<const __half2*>(h + (size_t)p.x * HIDC) + lane));
        a0 += c * f.x; a1 += c * f.y;
    }
    float di = dinv[node];
    float selfc = di * di;
    float2 fn = __half22float2(*(reinterpret_cast<const __half2*>(h + (size_t)node * HIDC) + lane));
    a0 += selfc * fn.x;
    a1 += selfc * fn.y;
    float2 bb = *(reinterpret_cast<const float2*>(bias) + lane);
    a0 = fmaxf(a0 + bb.x, 0.f);
    a1 = fmaxf(a1 + bb.y, 0.f);
    float2* op = reinterpret_cast<float2*>(out + (size_t)node * HIDC) + lane;
    *op = make_float2(a0, a1);
}

// ------ fused pool + MLP head: block per graph ----------------------------
__global__ __launch_bounds__(128) void pool_mlp_kernel(const float* __restrict__ h,
                                                       const int* __restrict__ batch,
                                                       const float* __restrict__ Wm1,
                                                       const float* __restrict__ bm1,
                                                       const float* __restrict__ Wm2,
                                                       const float* __restrict__ bm2,
                                                       float* __restrict__ out,
                                                       int n_nodes, int out_dim) {
    int g = blockIdx.x;
    int t = threadIdx.x;
    __shared__ int sb[2];
    if (t < 2) {
        int target = g + t;
        int lo = 0, hi = n_nodes;
        while (lo < hi) { int mid = (lo + hi) >> 1; if (batch[mid] < target) lo = mid + 1; else hi = mid; }
        sb[t] = lo;
    }
    __syncthreads();
    int beg = sb[0], end = sb[1];
    float p = 0.f;
    for (int i = beg; i < end; ++i) p += h[(size_t)i * 128 + t];
    __shared__ float row[128];
    __shared__ float z[128];
    row[t] = p;
    __syncthreads();
    float acc = bm1[t];
#pragma unroll 8
    for (int k = 0; k < 128; ++k) acc += row[k] * Wm1[k * 128 + t];
    z[t] = fmaxf(acc, 0.f);
    __syncthreads();
    if (t < out_dim) {
        float o = bm2[t];
#pragma unroll 8
        for (int k = 0; k < 128; ++k) o += z[k] * Wm2[k * out_dim + t];
        out[g * out_dim + t] = o;
    }
}

extern "C" void kernel_launch(void* const* d_in, const int* in_sizes, int n_in,
                              void* d_out, int out_size, void* d_ws, size_t ws_size,
                              hipStream_t stream) {
    const float* x   = (const float*)d_in[0];
    const int*   ei  = (const int*)d_in[1];
    const int*   bat = (const int*)d_in[2];
    const float* ea  = (const float*)d_in[3];
    const float* W1  = (const float*)d_in[4];
    const float* b1  = (const float*)d_in[5];
    const float* W2  = (const float*)d_in[6];
    const float* b2  = (const float*)d_in[7];
    const float* Wm1 = (const float*)d_in[8];
    const float* bm1 = (const float*)d_in[9];
    const float* Wm2 = (const float*)d_in[10];
    const float* bm2 = (const float*)d_in[11];
    float* out = (float*)d_out;

    const int N = in_sizes[2];           // 50000 nodes
    const int E = in_sizes[1] / 2;       // 1.6M edges
    const int N_GRAPHS = 512;
    const int OUT_DIM = out_size / N_GRAPHS;  // 10

    // workspace layout (all 256B-aligned)
    char* ws = (char*)d_ws;
    size_t off = 0;
    auto alloc = [&](size_t bytes) { char* p = ws + off; off += (bytes + 255) & ~size_t(255); return p; };
    __half* bufH    = (__half*)alloc((size_t)N * HIDC * 2);  // h1 then h2 (gathered, fp16)
    float*  bufB    = (float*)alloc((size_t)N * HIDC * 4);   // hr1 then hr2 (fp32)
    int2*   csr     = (int2*) alloc((size_t)E * 8);
    int*    rank    = (int*)  alloc((size_t)E * 4);
    unsigned long long* degcnt = (unsigned long long*)alloc((size_t)N * NSHARD * 8);
    int*    soff    = (int*)  alloc((size_t)N * NSHARD * 4);
    float*  dinv    = (float*)alloc((size_t)N * 4);
    int*    cnt     = (int*)  alloc((size_t)N * 4);
    int*    rowptr  = (int*)  alloc((size_t)(N + 1) * 4);
    int*    blocksum= (int*)  alloc(1024);
    int*    blockoff= (int*)  alloc(1024);

    const int B = 256;
    int gN = (N + B - 1) / B;            // 196 blocks
    int gE = (E + B - 1) / B;
    int gN4 = (N * NSHARD + B - 1) / B;

    // 1. zero degcnt planes
    init_kernel<<<gN4, B, 0, stream>>>(degcnt, N * NSHARD);
    // 2. sharded hist: packed degree+count atomic, shard-local rank
    hist_kernel<<<gE, B, 0, stream>>>(ei, ea, degcnt, rank, E, N);
    // 3a. dinv + cnt + shard offsets + block sums
    dinv_blocksum_kernel<<<gN, B, 0, stream>>>(degcnt, dinv, cnt, soff, blocksum, N);
    // 3b. scan block sums
    scan_blocksums_kernel<<<1, 256, 0, stream>>>(blocksum, blockoff, gN);
    // 3c. rowptr
    rowptr_kernel<<<gN, B, 0, stream>>>(cnt, blockoff, rowptr, N);
    // 4. CSR fill (atomic-free scatter)
    fill_kernel<<<gE, B, 0, stream>>>(ei, ea, dinv, rowptr, soff, rank, csr, E, N);
    // 5. h1 = x @ W1  (fp16 out)
    gemm_tiled<64><<<(N + 15) / 16, 256, 0, stream>>>(x, W1, bufH, N);
    // 6. hr1 = relu(aggregate(h1) + b1)  (fp32)
    agg_kernel<<<(N + 3) / 4, 256, 0, stream>>>(bufH, rowptr, csr, dinv, b1, bufB, N);
    // 7. h2 = hr1 @ W2  (fp16 out)
    gemm_tiled<128><<<(N + 15) / 16, 256, 0, stream>>>(bufB, W2, bufH, N);
    // 8. hr2 = relu(aggregate(h2) + b2)  (fp32)
    agg_kernel<<<(N + 3) / 4, 256, 0, stream>>>(bufH, rowptr, csr, dinv, b2, bufB, N);
    // 9. fused pool + MLP head
    pool_mlp_kernel<<<N_GRAPHS, 128, 0, stream>>>(bufB, bat, Wm1, bm1, Wm2, bm2, out, N, OUT_DIM);
}